// Round 2
// baseline (101.709 us; speedup 1.0000x reference)
//
#include <hip/hip_runtime.h>

// Inverse 2D Haar, fp32. Shapes: in 4x(16,64,128,128) -> out (16,64,256,256).
// Memory-bound streaming: 256 MiB read + 256 MiB write, zero reuse.
//
// One thread handles 4 input columns (float4 from each subband, 16B/lane
// coalescing sweet spot) and writes 4x float4: two per output row (2i, 2i+1).
// Adjacent lanes write adjacent 32B chunks -> fully coalesced stores.

__global__ __launch_bounds__(256) void ihaar_kernel(
    const float4* __restrict__ LL, const float4* __restrict__ LH,
    const float4* __restrict__ HL, const float4* __restrict__ HH,
    float4* __restrict__ out, int nQuads)
{
    int t = blockIdx.x * blockDim.x + threadIdx.x;
    if (t >= nQuads) return;

    // t = ((bc*H + i) * W4 + j4); W4 = W/4 = 32, H = 128
    int j4   = t & 31;
    int i    = (t >> 5) & 127;
    int bc   = t >> 12;

    float4 ll = LL[t];
    float4 lh = LH[t];
    float4 hl = HL[t];
    float4 hh = HH[t];

    float tl[4], tr[4], bl[4], br[4];
    {
        const float* pll = &ll.x; const float* plh = &lh.x;
        const float* phl = &hl.x; const float* phh = &hh.x;
        #pragma unroll
        for (int k = 0; k < 4; ++k) {
            float a = pll[k] + plh[k];
            float b = pll[k] - plh[k];
            float c = phl[k] + phh[k];
            float d = phl[k] - phh[k];
            tl[k] = 0.25f * (a + c);
            tr[k] = 0.25f * (a - c);
            bl[k] = 0.25f * (b + d);
            br[k] = 0.25f * (b - d);
        }
    }

    // Output rows: row0 = bc*256 + 2*i; 64 float4 per output row.
    int row0    = (bc << 8) + (i << 1);
    int rowBase = (row0 << 6);          // row0 * 64
    int o0 = rowBase + (j4 << 1);       // top row, first float4
    int o1 = o0 + 64;                   // bottom row, first float4

    out[o0]     = make_float4(tl[0], tr[0], tl[1], tr[1]);
    out[o0 + 1] = make_float4(tl[2], tr[2], tl[3], tr[3]);
    out[o1]     = make_float4(bl[0], br[0], bl[1], br[1]);
    out[o1 + 1] = make_float4(bl[2], br[2], bl[3], br[3]);
}

extern "C" void kernel_launch(void* const* d_in, const int* in_sizes, int n_in,
                              void* d_out, int out_size, void* d_ws, size_t ws_size,
                              hipStream_t stream) {
    const float4* LL = (const float4*)d_in[0];
    const float4* LH = (const float4*)d_in[1];
    const float4* HL = (const float4*)d_in[2];
    const float4* HH = (const float4*)d_in[3];
    float4* out = (float4*)d_out;

    int n = in_sizes[0];          // 16*64*128*128 = 16,777,216
    int nQuads = n >> 2;          // 4,194,304 float4 units
    int block = 256;
    int grid = (nQuads + block - 1) / block;   // 16384 blocks

    hipLaunchKernelGGL(ihaar_kernel, dim3(grid), dim3(block), 0, stream,
                       LL, LH, HL, HH, out, nQuads);
}

// Round 4
// 87.321 us; speedup vs baseline: 1.1648x; 1.1648x over previous
//
#include <hip/hip_runtime.h>

// Inverse 2D Haar, fp32. in 4x(16,64,128,128) -> out (16,64,256,256).
// Memory-bound streaming, zero reuse: 256 MiB read + 256 MiB write.
//
// Round-1 structure (float2 loads, fully contiguous 16B stores per
// instruction) + nontemporal hints (nt flag) to avoid cache allocate on
// streams that are never re-read. Uses ext_vector_type since the
// nontemporal builtins reject HIP_vector_type structs.

typedef float f32x2 __attribute__((ext_vector_type(2)));
typedef float f32x4 __attribute__((ext_vector_type(4)));

__global__ __launch_bounds__(256) void ihaar_kernel(
    const f32x2* __restrict__ LL, const f32x2* __restrict__ LH,
    const f32x2* __restrict__ HL, const f32x2* __restrict__ HH,
    f32x4* __restrict__ out, int nPairs)
{
    int t = blockIdx.x * blockDim.x + threadIdx.x;
    if (t >= nPairs) return;

    // t = ((bc*H + i) * W2 + j2), W2 = 64, H = 128
    int j2 = t & 63;
    int i  = (t >> 6) & 127;
    int bc = t >> 13;

    f32x2 ll = __builtin_nontemporal_load(&LL[t]);
    f32x2 lh = __builtin_nontemporal_load(&LH[t]);
    f32x2 hl = __builtin_nontemporal_load(&HL[t]);
    f32x2 hh = __builtin_nontemporal_load(&HH[t]);

    // column 0
    float a0 = ll.x + lh.x, b0 = ll.x - lh.x;
    float c0 = hl.x + hh.x, d0 = hl.x - hh.x;
    f32x4 top, bot;
    top.x = 0.25f * (a0 + c0); top.y = 0.25f * (a0 - c0);
    bot.x = 0.25f * (b0 + d0); bot.y = 0.25f * (b0 - d0);
    // column 1
    float a1 = ll.y + lh.y, b1 = ll.y - lh.y;
    float c1 = hl.y + hh.y, d1 = hl.y - hh.y;
    top.z = 0.25f * (a1 + c1); top.w = 0.25f * (a1 - c1);
    bot.z = 0.25f * (b1 + d1); bot.w = 0.25f * (b1 - d1);

    // Output: 64 f32x4 per output row; row0 = bc*256 + 2*i.
    int row0 = (bc << 8) + (i << 1);
    int o0 = (row0 << 6) + j2;
    int o1 = o0 + 64;

    __builtin_nontemporal_store(top, &out[o0]);
    __builtin_nontemporal_store(bot, &out[o1]);
}

extern "C" void kernel_launch(void* const* d_in, const int* in_sizes, int n_in,
                              void* d_out, int out_size, void* d_ws, size_t ws_size,
                              hipStream_t stream) {
    const f32x2* LL = (const f32x2*)d_in[0];
    const f32x2* LH = (const f32x2*)d_in[1];
    const f32x2* HL = (const f32x2*)d_in[2];
    const f32x2* HH = (const f32x2*)d_in[3];
    f32x4* out = (f32x4*)d_out;

    int n = in_sizes[0];          // 16*64*128*128 = 16,777,216
    int nPairs = n >> 1;          // 8,388,608 float2 units
    int block = 256;
    int grid = (nPairs + block - 1) / block;   // 32768 blocks

    hipLaunchKernelGGL(ihaar_kernel, dim3(grid), dim3(block), 0, stream,
                       LL, LH, HL, HH, out, nPairs);
}